// Round 1
// baseline (3482.057 us; speedup 1.0000x reference)
//
#include <hip/hip_runtime.h>

// Problem constants (from reference)
constexpr int B_   = 4;
constexpr int N_   = 16384;
constexpr int NOUT = 1170;   // 16384 // 14
constexpr int D_   = 128;
constexpr int O_   = 256;

// ---------------- FPS kernel ----------------
// One block per batch. Each thread owns PPT points in registers.
// Exact-match discipline: distances computed with non-contracted f32 ops in
// the reference's association order; argmax tie-breaks to smallest index.
constexpr int TPB_FPS = 1024;
constexpr int PPT = N_ / TPB_FPS;   // 16 points per thread
constexpr int NW  = TPB_FPS / 64;   // 16 waves

__global__ __launch_bounds__(TPB_FPS, 4)
void fps_kernel(const float* __restrict__ pcd_x,
                int* __restrict__ sel,        // [B, NOUT] (workspace)
                float* __restrict__ out_c) {  // query_c [B, NOUT, 3]
  const int b = blockIdx.x;
  const int t = threadIdx.x;
  const float* __restrict__ P = pcd_x + (size_t)b * N_ * 3;

  float x[PPT], y[PPT], z[PPT], dm[PPT];
#pragma unroll
  for (int j = 0; j < PPT; ++j) {
    const int p = t + j * TPB_FPS;
    x[j] = P[p * 3 + 0];
    y[j] = P[p * 3 + 1];
    z[j] = P[p * 3 + 2];
    dm[j] = 1e10f;
  }

  __shared__ float2 s_best[NW];

  // step 0: deterministic start at index 0
  float lx = P[0], ly = P[1], lz = P[2];
  if (t == 0) {
    sel[b * NOUT + 0] = 0;
    out_c[((size_t)b * NOUT + 0) * 3 + 0] = lx;
    out_c[((size_t)b * NOUT + 0) * 3 + 1] = ly;
    out_c[((size_t)b * NOUT + 0) * 3 + 2] = lz;
  }

  for (int step = 1; step < NOUT; ++step) {
    float bv = -1.0f;
    int   bi = 0x7fffffff;
#pragma unroll
    for (int j = 0; j < PPT; ++j) {
      // EXACT np order: ((dx*dx + dy*dy) + dz*dz), no FMA contraction
      const float dx = __fsub_rn(x[j], lx);
      const float dy = __fsub_rn(y[j], ly);
      const float dz = __fsub_rn(z[j], lz);
      float s = __fadd_rn(__fmul_rn(dx, dx), __fmul_rn(dy, dy));
      s = __fadd_rn(s, __fmul_rn(dz, dz));
      const float nd = fminf(dm[j], s);
      dm[j] = nd;
      // strict '>' keeps the earliest index within this thread (ascending j)
      if (nd > bv) { bv = nd; bi = t + j * TPB_FPS; }
    }

    // wave-level reduce (64 lanes), tie-break to smaller global index
#pragma unroll
    for (int off = 32; off > 0; off >>= 1) {
      const float ov = __shfl_down(bv, off, 64);
      const int   oi = __shfl_down(bi, off, 64);
      if (ov > bv || (ov == bv && oi < bi)) { bv = ov; bi = oi; }
    }
    if ((t & 63) == 0) s_best[t >> 6] = make_float2(bv, __int_as_float(bi));
    __syncthreads();

    // redundant cross-wave reduce by every thread (no second serial hop)
    float rv = s_best[0].x;
    int   ri = __float_as_int(s_best[0].y);
#pragma unroll
    for (int w = 1; w < NW; ++w) {
      const float ov = s_best[w].x;
      const int   oi = __float_as_int(s_best[w].y);
      if (ov > rv || (ov == rv && oi < ri)) { rv = ov; ri = oi; }
    }

    // broadcast-load the winner's coords (same address -> L1/L2 broadcast)
    lx = P[ri * 3 + 0];
    ly = P[ri * 3 + 1];
    lz = P[ri * 3 + 2];
    if (t == 0) {
      sel[b * NOUT + step] = ri;
      out_c[((size_t)b * NOUT + step) * 3 + 0] = lx;
      out_c[((size_t)b * NOUT + step) * 3 + 1] = ly;
      out_c[((size_t)b * NOUT + step) * 3 + 2] = lz;
    }
    __syncthreads();  // protect s_best before next iteration's writes
  }
}

// ---------------- projection + gathers ----------------
// out_query_f[row, :] = tgt[b, sel[row], :] @ W + bias ; rows = B*NOUT.
// 4 rows per 256-thread block; thread t owns output column t.
constexpr int TPB_PROJ = 256;
constexpr int RPB = 4;

__global__ __launch_bounds__(TPB_PROJ)
void proj_kernel(const float* __restrict__ tgt,
                 const float* __restrict__ pcd_v,
                 const float* __restrict__ W,
                 const float* __restrict__ bias,
                 const int* __restrict__ sel,
                 float* __restrict__ out_f,    // [B*NOUT, 256]
                 float* __restrict__ out_v) {  // [B*NOUT, 9]
  const int t = threadIdx.x;
  const int row0 = blockIdx.x * RPB;

  __shared__ float sA[RPB * D_];
  __shared__ int   sIdx[RPB];

  if (t < RPB) {
    const int row = row0 + t;
    const int b = row / NOUT;
    sIdx[t] = b * N_ + sel[row];   // absolute point index in [B*N)
  }
  __syncthreads();

#pragma unroll
  for (int l = 0; l < RPB * D_ / TPB_PROJ; ++l) {  // 2 iterations
    const int e = t + l * TPB_PROJ;
    const int r = e >> 7;
    const int k = e & (D_ - 1);
    sA[e] = tgt[(size_t)sIdx[r] * D_ + k];
  }
  __syncthreads();

  float acc0 = 0.f, acc1 = 0.f, acc2 = 0.f, acc3 = 0.f;
#pragma unroll 8
  for (int k = 0; k < D_; ++k) {
    const float w = W[k * O_ + t];       // coalesced across threads
    acc0 = fmaf(sA[0 * D_ + k], w, acc0);  // LDS broadcast reads
    acc1 = fmaf(sA[1 * D_ + k], w, acc1);
    acc2 = fmaf(sA[2 * D_ + k], w, acc2);
    acc3 = fmaf(sA[3 * D_ + k], w, acc3);
  }
  const float bb = bias[t];
  out_f[(size_t)(row0 + 0) * O_ + t] = acc0 + bb;
  out_f[(size_t)(row0 + 1) * O_ + t] = acc1 + bb;
  out_f[(size_t)(row0 + 2) * O_ + t] = acc2 + bb;
  out_f[(size_t)(row0 + 3) * O_ + t] = acc3 + bb;

  // query_v gather: 4 rows x 9 floats
  if (t < RPB * 9) {
    const int r = t / 9;
    const int e = t - r * 9;
    out_v[(size_t)(row0 + r) * 9 + e] = pcd_v[(size_t)sIdx[r] * 9 + e];
  }
}

extern "C" void kernel_launch(void* const* d_in, const int* in_sizes, int n_in,
                              void* d_out, int out_size, void* d_ws, size_t ws_size,
                              hipStream_t stream) {
  const float* tgt   = (const float*)d_in[0];  // [4,16384,128]
  const float* pcd_x = (const float*)d_in[1];  // [4,16384,3]
  const float* pcd_v = (const float*)d_in[2];  // [4,16384,3,3]
  const float* W     = (const float*)d_in[3];  // [128,256]
  const float* bias  = (const float*)d_in[4];  // [256]

  float* out   = (float*)d_out;
  float* out_f = out;                                   // [4,1170,256]
  float* out_c = out + (size_t)B_ * NOUT * O_;          // [4,1170,3]
  float* out_v = out_c + (size_t)B_ * NOUT * 3;         // [4,1170,3,3]

  int* sel = (int*)d_ws;  // [4,1170] int32

  hipLaunchKernelGGL(fps_kernel, dim3(B_), dim3(TPB_FPS), 0, stream,
                     pcd_x, sel, out_c);
  hipLaunchKernelGGL(proj_kernel, dim3(B_ * NOUT / RPB), dim3(TPB_PROJ), 0, stream,
                     tgt, pcd_v, W, bias, sel, out_f, out_v);
}

// Round 2
// 2030.912 us; speedup vs baseline: 1.7145x; 1.7145x over previous
//
#include <hip/hip_runtime.h>

// Problem constants (from reference)
constexpr int B_   = 4;
constexpr int N_   = 16384;
constexpr int NOUT = 1170;   // 16384 // 14
constexpr int D_   = 128;
constexpr int O_   = 256;

typedef float f32x2 __attribute__((ext_vector_type(2)));

// ---------------- FPS kernel ----------------
// One block per batch. 512 threads x 32 points, held as 16 float2 pairs so
// clang can emit v_pk_{add,mul}_f32 (exact same rounding as scalar; fp
// contraction disabled locally to forbid pk_fma). Argmax via u64 key
// (distbits<<32 | ~idx): u64 max == argmax with smallest-index tie-break.
constexpr int TPB_FPS = 512;
constexpr int PPT   = N_ / TPB_FPS;  // 32 points per thread
constexpr int NPAIR = PPT / 2;       // 16 float2 pairs
constexpr int NW    = TPB_FPS / 64;  // 8 waves

__global__ __launch_bounds__(TPB_FPS, 2)
void fps_kernel(const float* __restrict__ pcd_x,
                int* __restrict__ sel,        // [B, NOUT] (workspace)
                float* __restrict__ out_c) {  // query_c [B, NOUT, 3]
  const int b = blockIdx.x;
  const int t = threadIdx.x;
  const float* __restrict__ P = pcd_x + (size_t)b * N_ * 3;

  f32x2 x[NPAIR], y[NPAIR], z[NPAIR], dm[NPAIR];
#pragma unroll
  for (int k = 0; k < NPAIR; ++k) {
    const int p0 = t + (2 * k) * TPB_FPS;
    const int p1 = t + (2 * k + 1) * TPB_FPS;
    x[k]  = f32x2{P[p0 * 3 + 0], P[p1 * 3 + 0]};
    y[k]  = f32x2{P[p0 * 3 + 1], P[p1 * 3 + 1]};
    z[k]  = f32x2{P[p0 * 3 + 2], P[p1 * 3 + 2]};
    dm[k] = f32x2{1e10f, 1e10f};
  }

  __shared__ unsigned long long s_key[2][NW];  // double-buffered per-wave bests

  // step 0: deterministic start at index 0
  float lx = P[0], ly = P[1], lz = P[2];
  if (t == 0) {
    sel[b * NOUT + 0] = 0;
    out_c[((size_t)b * NOUT + 0) * 3 + 0] = lx;
    out_c[((size_t)b * NOUT + 0) * 3 + 1] = ly;
    out_c[((size_t)b * NOUT + 0) * 3 + 2] = lz;
  }

  for (int step = 1; step < NOUT; ++step) {
    const f32x2 lxx = {lx, lx}, lyy = {ly, ly}, lzz = {lz, lz};
    f32x2 bv2 = {-1.0f, -1.0f};
    {
#pragma clang fp contract(off)
#pragma unroll
      for (int k = 0; k < NPAIR; ++k) {
        // EXACT np order per component: ((dx*dx + dy*dy) + dz*dz), no FMA
        const f32x2 dx = x[k] - lxx;
        const f32x2 dy = y[k] - lyy;
        const f32x2 dz = z[k] - lzz;
        const f32x2 s  = (dx * dx + dy * dy) + dz * dz;
        f32x2 nd;
        nd.x = fminf(dm[k].x, s.x);
        nd.y = fminf(dm[k].y, s.y);
        dm[k] = nd;
        bv2.x = fmaxf(bv2.x, nd.x);
        bv2.y = fmaxf(bv2.y, nd.y);
      }
    }
    const float bv = fmaxf(bv2.x, bv2.y);

    // descending re-scan: last write wins -> smallest global index with dm==bv
    int bi = 0;
#pragma unroll
    for (int k = NPAIR - 1; k >= 0; --k) {
      if (dm[k].y == bv) bi = t + (2 * k + 1) * TPB_FPS;
      if (dm[k].x == bv) bi = t + (2 * k) * TPB_FPS;
    }

    // u64 key: (value bits << 32) | ~idx  — dist >= 0 so bits are monotone;
    // max over keys = max value, ties -> smallest index.
    unsigned long long key =
        ((unsigned long long)__float_as_uint(bv) << 32) | (unsigned int)(~bi);

    // 64-lane butterfly reduce
#pragma unroll
    for (int off = 32; off > 0; off >>= 1) {
      const unsigned long long ok = __shfl_xor(key, off, 64);
      if (ok > key) key = ok;
    }
    if ((t & 63) == 0) s_key[step & 1][t >> 6] = key;
    __syncthreads();  // single barrier per step (double-buffered s_key)

    // redundant cross-wave reduce (8 entries, broadcast reads)
    unsigned long long kmax = s_key[step & 1][0];
#pragma unroll
    for (int w = 1; w < NW; ++w) {
      const unsigned long long kw = s_key[step & 1][w];
      if (kw > kmax) kmax = kw;
    }
    int ri = ~(unsigned int)kmax;
    ri = __builtin_amdgcn_readfirstlane(ri);  // wave-uniform -> scalar loads

    lx = P[ri * 3 + 0];
    ly = P[ri * 3 + 1];
    lz = P[ri * 3 + 2];
    if (t == 0) {
      sel[b * NOUT + step] = ri;
      out_c[((size_t)b * NOUT + step) * 3 + 0] = lx;
      out_c[((size_t)b * NOUT + step) * 3 + 1] = ly;
      out_c[((size_t)b * NOUT + step) * 3 + 2] = lz;
    }
  }
}

// ---------------- projection + gathers ----------------
// out_query_f[row, :] = tgt[b, sel[row], :] @ W + bias ; rows = B*NOUT.
// 4 rows per 256-thread block; thread t owns output column t.
constexpr int TPB_PROJ = 256;
constexpr int RPB = 4;

__global__ __launch_bounds__(TPB_PROJ)
void proj_kernel(const float* __restrict__ tgt,
                 const float* __restrict__ pcd_v,
                 const float* __restrict__ W,
                 const float* __restrict__ bias,
                 const int* __restrict__ sel,
                 float* __restrict__ out_f,    // [B*NOUT, 256]
                 float* __restrict__ out_v) {  // [B*NOUT, 9]
  const int t = threadIdx.x;
  const int row0 = blockIdx.x * RPB;

  __shared__ float sA[RPB * D_];
  __shared__ int   sIdx[RPB];

  if (t < RPB) {
    const int row = row0 + t;
    const int b = row / NOUT;
    sIdx[t] = b * N_ + sel[row];   // absolute point index in [B*N)
  }
  __syncthreads();

#pragma unroll
  for (int l = 0; l < RPB * D_ / TPB_PROJ; ++l) {  // 2 iterations
    const int e = t + l * TPB_PROJ;
    const int r = e >> 7;
    const int k = e & (D_ - 1);
    sA[e] = tgt[(size_t)sIdx[r] * D_ + k];
  }
  __syncthreads();

  float acc0 = 0.f, acc1 = 0.f, acc2 = 0.f, acc3 = 0.f;
#pragma unroll 8
  for (int k = 0; k < D_; ++k) {
    const float w = W[k * O_ + t];       // coalesced across threads
    acc0 = fmaf(sA[0 * D_ + k], w, acc0);  // LDS broadcast reads
    acc1 = fmaf(sA[1 * D_ + k], w, acc1);
    acc2 = fmaf(sA[2 * D_ + k], w, acc2);
    acc3 = fmaf(sA[3 * D_ + k], w, acc3);
  }
  const float bb = bias[t];
  out_f[(size_t)(row0 + 0) * O_ + t] = acc0 + bb;
  out_f[(size_t)(row0 + 1) * O_ + t] = acc1 + bb;
  out_f[(size_t)(row0 + 2) * O_ + t] = acc2 + bb;
  out_f[(size_t)(row0 + 3) * O_ + t] = acc3 + bb;

  // query_v gather: 4 rows x 9 floats
  if (t < RPB * 9) {
    const int r = t / 9;
    const int e = t - r * 9;
    out_v[(size_t)(row0 + r) * 9 + e] = pcd_v[(size_t)sIdx[r] * 9 + e];
  }
}

extern "C" void kernel_launch(void* const* d_in, const int* in_sizes, int n_in,
                              void* d_out, int out_size, void* d_ws, size_t ws_size,
                              hipStream_t stream) {
  const float* tgt   = (const float*)d_in[0];  // [4,16384,128]
  const float* pcd_x = (const float*)d_in[1];  // [4,16384,3]
  const float* pcd_v = (const float*)d_in[2];  // [4,16384,3,3]
  const float* W     = (const float*)d_in[3];  // [128,256]
  const float* bias  = (const float*)d_in[4];  // [256]

  float* out   = (float*)d_out;
  float* out_f = out;                                   // [4,1170,256]
  float* out_c = out + (size_t)B_ * NOUT * O_;          // [4,1170,3]
  float* out_v = out_c + (size_t)B_ * NOUT * 3;         // [4,1170,3,3]

  int* sel = (int*)d_ws;  // [4,1170] int32

  hipLaunchKernelGGL(fps_kernel, dim3(B_), dim3(TPB_FPS), 0, stream,
                     pcd_x, sel, out_c);
  hipLaunchKernelGGL(proj_kernel, dim3(B_ * NOUT / RPB), dim3(TPB_PROJ), 0, stream,
                     tgt, pcd_v, W, bias, sel, out_f, out_v);
}

// Round 3
// 1836.798 us; speedup vs baseline: 1.8957x; 1.1057x over previous
//
#include <hip/hip_runtime.h>

// Problem constants (from reference)
constexpr int B_   = 4;
constexpr int N_   = 16384;
constexpr int NOUT = 1170;   // 16384 // 14
constexpr int D_   = 128;
constexpr int O_   = 256;

typedef float f32x2 __attribute__((ext_vector_type(2)));

// ---------------- FPS kernel ----------------
// One block per batch. 512 threads x 32 points held as 16 f32x2 pairs
// (v_pk_{add,mul}_f32; same rounding as scalar — fp contraction off locally).
// amdgpu_waves_per_eu(2,2): with one 8-wave block per CU the true budget is
// 256 VGPR/wave; without it the allocator targets phantom occupancy and
// spills the point arrays to scratch (round-2: VGPR_Count=88 < 128 needed).
// Reduce chain: f32 value-only wave reduce -> LDS -> block max; only the
// winning thread rescans for its index and atomicMin's it (exact np
// first-max tie-break: descending in-thread scan + min global index).
constexpr int TPB_FPS = 512;
constexpr int PPT   = N_ / TPB_FPS;  // 32 points per thread
constexpr int NPAIR = PPT / 2;       // 16 f32x2 pairs
constexpr int NW    = TPB_FPS / 64;  // 8 waves

__global__ __launch_bounds__(TPB_FPS)
__attribute__((amdgpu_waves_per_eu(2, 2)))
void fps_kernel(const float* __restrict__ pcd_x,
                int* __restrict__ sel,        // [B, NOUT] (workspace)
                float* __restrict__ out_c) {  // query_c [B, NOUT, 3]
  const int b = blockIdx.x;
  const int t = threadIdx.x;
  const float* __restrict__ P = pcd_x + (size_t)b * N_ * 3;

  f32x2 x[NPAIR], y[NPAIR], z[NPAIR], dm[NPAIR];
#pragma unroll
  for (int k = 0; k < NPAIR; ++k) {
    const int p0 = t + (2 * k) * TPB_FPS;
    const int p1 = t + (2 * k + 1) * TPB_FPS;
    x[k]  = f32x2{P[p0 * 3 + 0], P[p1 * 3 + 0]};
    y[k]  = f32x2{P[p0 * 3 + 1], P[p1 * 3 + 1]};
    z[k]  = f32x2{P[p0 * 3 + 2], P[p1 * 3 + 2]};
    dm[k] = f32x2{1e10f, 1e10f};
  }

  __shared__ float s_val[NW] __attribute__((aligned(16)));
  __shared__ int   s_idx[2];   // double-buffered winner index (by step parity)

  // step 0: deterministic start at index 0
  float lx = P[0], ly = P[1], lz = P[2];
  if (t == 0) {
    s_idx[1] = 0x7fffffff;  // slot for step 1 (ordered by BAR-A of step 1)
    sel[b * NOUT + 0] = 0;
    out_c[((size_t)b * NOUT + 0) * 3 + 0] = lx;
    out_c[((size_t)b * NOUT + 0) * 3 + 1] = ly;
    out_c[((size_t)b * NOUT + 0) * 3 + 2] = lz;
  }

  for (int step = 1; step < NOUT; ++step) {
    const int p = step & 1;
    const f32x2 lxx = {lx, lx}, lyy = {ly, ly}, lzz = {lz, lz};
    f32x2 bv2 = {-1.0f, -1.0f};
    {
#pragma clang fp contract(off)
#pragma unroll
      for (int k = 0; k < NPAIR; ++k) {
        // EXACT np order per component: ((dx*dx + dy*dy) + dz*dz), no FMA
        const f32x2 dx = x[k] - lxx;
        const f32x2 dy = y[k] - lyy;
        const f32x2 dz = z[k] - lzz;
        const f32x2 s  = (dx * dx + dy * dy) + dz * dz;
        f32x2 nd;
        nd.x = fminf(dm[k].x, s.x);
        nd.y = fminf(dm[k].y, s.y);
        dm[k] = nd;
        bv2.x = fmaxf(bv2.x, nd.x);
        bv2.y = fmaxf(bv2.y, nd.y);
      }
    }
    const float bv = fmaxf(bv2.x, bv2.y);

    // f32 value-only wave reduce (max preserves exact bits of one input)
    float wmax = bv;
#pragma unroll
    for (int off = 32; off > 0; off >>= 1)
      wmax = fmaxf(wmax, __shfl_xor(wmax, off, 64));
    if ((t & 63) == 0) s_val[t >> 6] = wmax;
    __syncthreads();  // BAR-A

    // block max from 8 wave maxima (two ds_read_b128)
    const float4 v0 = *reinterpret_cast<const float4*>(&s_val[0]);
    const float4 v1 = *reinterpret_cast<const float4*>(&s_val[4]);
    const float gbv = fmaxf(fmaxf(fmaxf(v0.x, v0.y), fmaxf(v0.z, v0.w)),
                            fmaxf(fmaxf(v1.x, v1.y), fmaxf(v1.z, v1.w)));

    // reset the OTHER parity slot inside the [BAR-A, BAR-B] window:
    // its readers finished before BAR-A, its writers start after next BAR-A.
    if (t == 0) s_idx[p ^ 1] = 0x7fffffff;

    // only the owner(s) of the block max rescan (usually exactly 1 thread)
    if (bv == gbv) {
      int bi = 0;
#pragma unroll
      for (int k = NPAIR - 1; k >= 0; --k) {  // descending: last write = min idx
        if (dm[k].y == bv) bi = t + (2 * k + 1) * TPB_FPS;
        if (dm[k].x == bv) bi = t + (2 * k) * TPB_FPS;
      }
      atomicMin(&s_idx[p], bi);  // min global index across tied threads
    }
    __syncthreads();  // BAR-B

    int ri = s_idx[p];
    ri = __builtin_amdgcn_readfirstlane(ri);  // wave-uniform -> scalar loads
    lx = P[ri * 3 + 0];
    ly = P[ri * 3 + 1];
    lz = P[ri * 3 + 2];
    if (t == 0) {
      sel[b * NOUT + step] = ri;
      out_c[((size_t)b * NOUT + step) * 3 + 0] = lx;
      out_c[((size_t)b * NOUT + step) * 3 + 1] = ly;
      out_c[((size_t)b * NOUT + step) * 3 + 2] = lz;
    }
  }
}

// ---------------- projection + gathers ----------------
// out_query_f[row, :] = tgt[b, sel[row], :] @ W + bias ; rows = B*NOUT.
// 4 rows per 256-thread block; thread t owns output column t.
constexpr int TPB_PROJ = 256;
constexpr int RPB = 4;

__global__ __launch_bounds__(TPB_PROJ)
void proj_kernel(const float* __restrict__ tgt,
                 const float* __restrict__ pcd_v,
                 const float* __restrict__ W,
                 const float* __restrict__ bias,
                 const int* __restrict__ sel,
                 float* __restrict__ out_f,    // [B*NOUT, 256]
                 float* __restrict__ out_v) {  // [B*NOUT, 9]
  const int t = threadIdx.x;
  const int row0 = blockIdx.x * RPB;

  __shared__ float sA[RPB * D_];
  __shared__ int   sIdx[RPB];

  if (t < RPB) {
    const int row = row0 + t;
    const int b = row / NOUT;
    sIdx[t] = b * N_ + sel[row];   // absolute point index in [B*N)
  }
  __syncthreads();

#pragma unroll
  for (int l = 0; l < RPB * D_ / TPB_PROJ; ++l) {  // 2 iterations
    const int e = t + l * TPB_PROJ;
    const int r = e >> 7;
    const int k = e & (D_ - 1);
    sA[e] = tgt[(size_t)sIdx[r] * D_ + k];
  }
  __syncthreads();

  float acc0 = 0.f, acc1 = 0.f, acc2 = 0.f, acc3 = 0.f;
#pragma unroll 8
  for (int k = 0; k < D_; ++k) {
    const float w = W[k * O_ + t];       // coalesced across threads
    acc0 = fmaf(sA[0 * D_ + k], w, acc0);  // LDS broadcast reads
    acc1 = fmaf(sA[1 * D_ + k], w, acc1);
    acc2 = fmaf(sA[2 * D_ + k], w, acc2);
    acc3 = fmaf(sA[3 * D_ + k], w, acc3);
  }
  const float bb = bias[t];
  out_f[(size_t)(row0 + 0) * O_ + t] = acc0 + bb;
  out_f[(size_t)(row0 + 1) * O_ + t] = acc1 + bb;
  out_f[(size_t)(row0 + 2) * O_ + t] = acc2 + bb;
  out_f[(size_t)(row0 + 3) * O_ + t] = acc3 + bb;

  // query_v gather: 4 rows x 9 floats
  if (t < RPB * 9) {
    const int r = t / 9;
    const int e = t - r * 9;
    out_v[(size_t)(row0 + r) * 9 + e] = pcd_v[(size_t)sIdx[r] * 9 + e];
  }
}

extern "C" void kernel_launch(void* const* d_in, const int* in_sizes, int n_in,
                              void* d_out, int out_size, void* d_ws, size_t ws_size,
                              hipStream_t stream) {
  const float* tgt   = (const float*)d_in[0];  // [4,16384,128]
  const float* pcd_x = (const float*)d_in[1];  // [4,16384,3]
  const float* pcd_v = (const float*)d_in[2];  // [4,16384,3,3]
  const float* W     = (const float*)d_in[3];  // [128,256]
  const float* bias  = (const float*)d_in[4];  // [256]

  float* out   = (float*)d_out;
  float* out_f = out;                                   // [4,1170,256]
  float* out_c = out + (size_t)B_ * NOUT * O_;          // [4,1170,3]
  float* out_v = out_c + (size_t)B_ * NOUT * 3;         // [4,1170,3,3]

  int* sel = (int*)d_ws;  // [4,1170] int32

  hipLaunchKernelGGL(fps_kernel, dim3(B_), dim3(TPB_FPS), 0, stream,
                     pcd_x, sel, out_c);
  hipLaunchKernelGGL(proj_kernel, dim3(B_ * NOUT / RPB), dim3(TPB_PROJ), 0, stream,
                     tgt, pcd_v, W, bias, sel, out_f, out_v);
}